// Round 1
// baseline (307.850 us; speedup 1.0000x reference)
//
#include <hip/hip_runtime.h>
#include <stddef.h>

// out[n,j,h,w] = sum_{k,i} x[n,i,(h+55)%56, srccol(k,w)] * w[j,k,i]
//   tap k=0: valid w>=1,  col (w+54)%56
//   tap k=1: always,      col (w+55)%56
//   tap k=2: valid w<=54, col w
// GEMM view: M=32 (j), K=384 (tap*128+i), N=spatial. bf16 MFMA 16x16x32.
// Block = (n, 4 output rows h0..h0+3) -> reads source rows h0-1..h0+2, which
// are CONTIGUOUS in x per channel: 896B HBM granules (keep!).
// R1 change: 512 threads / 8 waves per block (was 256/4). LDS (62KB) still
// allows 2 blocks/CU -> 16 waves/CU (2x prior occupancy) for more in-flight
// staging loads + finer stage/compute overlap. Each wave stages 16 channel
// iters (ch = p*8+grp) and computes one (row, col-half): acc[2][2].

#define C_IN   128
#define C_OUT  32
#define HH     56
#define WW     56
#define HW     3136
#define KTOT   384
#define WSTRIDE 392              // padded K-stride for weights (bf16 elems)
#define XSTRIDE 136              // ushorts per col (272B = 17x16B -> bank-balanced b128)
#define XROWSZ (57 * XSTRIDE)    // one source row: 56 real cols + zero col 56

typedef short bf16x8 __attribute__((ext_vector_type(8)));
typedef float f32x4  __attribute__((ext_vector_type(4)));

static __device__ __forceinline__ unsigned short f2b(float f) {
    unsigned u = __builtin_bit_cast(unsigned, f);
    unsigned r = u + 0x7FFFu + ((u >> 16) & 1u);   // RNE
    return (unsigned short)(r >> 16);
}

__global__ void pack_w_kernel(const float* __restrict__ w, unsigned short* __restrict__ ws) {
    int idx = blockIdx.x * 256 + threadIdx.x;
    if (idx < C_OUT * WSTRIDE) {
        int j = idx / WSTRIDE;
        int r = idx % WSTRIDE;
        ws[idx] = f2b(r < KTOT ? w[j * KTOT + r] : 0.0f);
    }
}

__global__ __launch_bounds__(512, 4)
void conv_mfma_kernel(const float* __restrict__ x, const unsigned short* __restrict__ ws,
                      float* __restrict__ out) {
    const int bid  = blockIdx.x;
    const int n    = bid / (HH / 4);
    const int h0   = (bid % (HH / 4)) * 4;
    const int tid  = threadIdx.x;
    const int lane = tid & 63;
    const int grp  = tid >> 6;           // 0..7

    // XT[src row r (0..3)][col 0..56][ch] bf16; col 56 = zeros
    __shared__ __align__(16) unsigned short XT[4 * XROWSZ];   // 62016 B

    // zero col 56 of all 4 rows: 4*136 ushorts = 1088 B = 68 uint4
    if (tid < 68) {
        int r = tid / 17, off = (tid % 17) * 8;
        *(uint4*)&XT[r * XROWSZ + WW * XSTRIDE + off] = make_uint4(0, 0, 0, 0);
    }

    const float* xb = x + (size_t)n * (C_IN * HW);

    // ---- stage 4 source rows. wave-inst = one 896B contiguous granule ----
    // lane<56: q=lane -> (r=q/14, c4=q%14); ch = p*8 + grp. 16 iters/wave.
    {
        const int q  = lane;
        const int r  = q / 14;
        const int c4 = q % 14;
        const int hs = (h0 + 55 + r) % HH;          // source row for LDS row r
        const size_t rowoff = (size_t)hs * WW + c4 * 4;
        unsigned short* dst0 = &XT[r * XROWSZ + (c4 * 4) * XSTRIDE + grp];
        const float* src0 = xb + (size_t)grp * HW + rowoff;
#pragma unroll 8
        for (int p = 0; p < 16; ++p) {
            if (q < WW) {
                const float4 v = *(const float4*)(src0 + (size_t)(p * 8) * HW);
                unsigned short* dst = dst0 + p * 8;
                dst[0]           = f2b(v.x);
                dst[XSTRIDE]     = f2b(v.y);
                dst[2 * XSTRIDE] = f2b(v.z);
                dst[3 * XSTRIDE] = f2b(v.w);
            }
        }
    }
    __syncthreads();

    // ---- MFMA: wave grp -> row rr = grp>>1, col-half hf = grp&1 ----
    const int l15 = lane & 15;
    const int kb  = (lane >> 4) * 8;
    const int rr  = grp >> 1;
    const int hf  = grp & 1;
    const unsigned short* Xr = &XT[rr * XROWSZ];

    const unsigned short* bp[2][3];
#pragma unroll
    for (int ct2 = 0; ct2 < 2; ++ct2) {
        const int nn = (hf * 2 + ct2) * 16 + l15;
        const int cc0 = (nn >= 1 && nn <= 55) ? (nn + 54) % WW : WW;
        const int cc1 = (nn <= 55) ? (nn + 55) % WW : WW;
        const int cc2 = (nn <= 54) ? nn : WW;
        bp[ct2][0] = Xr + cc0 * XSTRIDE + kb;
        bp[ct2][1] = Xr + cc1 * XSTRIDE + kb;
        bp[ct2][2] = Xr + cc2 * XSTRIDE + kb;
    }

    const unsigned short* wp = ws + l15 * WSTRIDE + kb;

    f32x4 acc[2][2];
#pragma unroll
    for (int ct2 = 0; ct2 < 2; ++ct2) {
        acc[ct2][0] = (f32x4){0.f, 0.f, 0.f, 0.f};
        acc[ct2][1] = (f32x4){0.f, 0.f, 0.f, 0.f};
    }

#pragma unroll
    for (int c = 0; c < 12; ++c) {
        const int tap = c >> 2;
        const int ib  = (c & 3) * 32;
        bf16x8 A0 = *(const bf16x8*)(wp + c * 32);
        bf16x8 A1 = *(const bf16x8*)(wp + 16 * WSTRIDE + c * 32);
#pragma unroll
        for (int ct2 = 0; ct2 < 2; ++ct2) {
            bf16x8 B = *(const bf16x8*)(bp[ct2][tap] + ib);
            acc[ct2][0] = __builtin_amdgcn_mfma_f32_16x16x32_bf16(A0, B, acc[ct2][0], 0, 0, 0);
            acc[ct2][1] = __builtin_amdgcn_mfma_f32_16x16x32_bf16(A1, B, acc[ct2][1], 0, 0, 0);
        }
    }

    // ---- epilogue: C/D layout col=lane&15 (w), row=(lane>>4)*4+reg (j) ----
    {
        const int h  = h0 + rr;
        const int j0 = (lane >> 4) * 4;
        float* ob = out + (size_t)n * (C_OUT * HW) + (size_t)h * WW;
#pragma unroll
        for (int ct2 = 0; ct2 < 2; ++ct2) {
            const int nn = (hf * 2 + ct2) * 16 + l15;
            if (nn < WW) {
#pragma unroll
                for (int r = 0; r < 4; ++r) {
                    ob[(size_t)(j0 + r) * HW + nn]      = acc[ct2][0][r];
                    ob[(size_t)(j0 + r + 16) * HW + nn] = acc[ct2][1][r];
                }
            }
        }
    }
}

extern "C" void kernel_launch(void* const* d_in, const int* in_sizes, int n_in,
                              void* d_out, int out_size, void* d_ws, size_t ws_size,
                              hipStream_t stream) {
    const float* x = (const float*)d_in[0];
    const float* w = (const float*)d_in[1];
    float* out = (float*)d_out;
    unsigned short* ws = (unsigned short*)d_ws;   // 32*392*2 = 25088 B needed

    pack_w_kernel<<<(C_OUT * WSTRIDE + 255) / 256, 256, 0, stream>>>(w, ws);
    conv_mfma_kernel<<<dim3(128 * (HH / 4)), dim3(512), 0, stream>>>(x, ws, out);
}

// Round 3
// 303.041 us; speedup vs baseline: 1.0159x; 1.0159x over previous
//
#include <hip/hip_runtime.h>
#include <stddef.h>

// out[n,j,h,w] = sum_{k,i} x[n,i,(h+55)%56, srccol(k,w)] * w[j,k,i]
//   tap k=0: valid w>=1,  col (w+54)%56
//   tap k=1: always,      col (w+55)%56
//   tap k=2: valid w<=54, col w
// GEMM view: M=32 (j), K=384 (tap*128+i), N=spatial. bf16 MFMA 16x16x32.
// Block = (n, 4 output rows h0..h0+3) -> reads source rows h0-1..h0+2 which are
// CONTIGUOUS in x per channel: 896B HBM granules (keep!).
// R3 = R2 with the compile fix: pk2 via inline-asm v_cvt_pk_bf16_f32 (no
// builtin exists on gfx950; T12 recipe). Staging: each lane loads 8 channels
// (8x float4, coalesced), packs pairs with cvt_pk, writes ds_write_b128
// (8 contiguous ch). Replaces 64 scalar f2b + 64 ds_write_u16 (7-way
// bank-conflicted) with 32 cvt_pk + 8 b128 writes tiling all 32 banks.

#define C_IN   128
#define C_OUT  32
#define HH     56
#define WW     56
#define HW     3136
#define KTOT   384
#define WSTRIDE 392              // padded K-stride for weights (bf16 elems)
#define XSTRIDE 136              // ushorts per col (272B = 17x16B -> bank-balanced b128 reads)
#define XROWSZ (57 * XSTRIDE)    // one source row: 56 real cols + zero col 56

typedef short bf16x8 __attribute__((ext_vector_type(8)));
typedef float f32x4  __attribute__((ext_vector_type(4)));
typedef float f32x4v __attribute__((ext_vector_type(4)));

static __device__ __forceinline__ unsigned short f2b(float f) {
    unsigned u = __builtin_bit_cast(unsigned, f);
    unsigned r = u + 0x7FFFu + ((u >> 16) & 1u);   // RNE
    return (unsigned short)(r >> 16);
}

static __device__ __forceinline__ unsigned pk2(float lo, float hi) {
    unsigned r;
    asm("v_cvt_pk_bf16_f32 %0, %1, %2" : "=v"(r) : "v"(lo), "v"(hi));  // RNE
    return r;
}

__global__ void pack_w_kernel(const float* __restrict__ w, unsigned short* __restrict__ ws) {
    int idx = blockIdx.x * 256 + threadIdx.x;
    if (idx < C_OUT * WSTRIDE) {
        int j = idx / WSTRIDE;
        int r = idx % WSTRIDE;
        ws[idx] = f2b(r < KTOT ? w[j * KTOT + r] : 0.0f);
    }
}

__global__ __launch_bounds__(512, 4)
void conv_mfma_kernel(const float* __restrict__ x, const unsigned short* __restrict__ ws,
                      float* __restrict__ out) {
    const int bid  = blockIdx.x;
    const int n    = bid / (HH / 4);
    const int h0   = (bid % (HH / 4)) * 4;
    const int tid  = threadIdx.x;
    const int lane = tid & 63;
    const int grp  = tid >> 6;           // 0..7

    // XT[src row r (0..3)][col 0..56][ch] bf16; col 56 = zeros
    __shared__ __align__(16) unsigned short XT[4 * XROWSZ];   // 62016 B

    // zero col 56 of all 4 rows: 4*136 ushorts = 1088 B = 68 uint4
    if (tid < 68) {
        int r = tid / 17, off = (tid % 17) * 8;
        *(uint4*)&XT[r * XROWSZ + WW * XSTRIDE + off] = make_uint4(0, 0, 0, 0);
    }

    const float* xb = x + (size_t)n * (C_IN * HW);

    // ---- stage 4 source rows ----
    // lane q<56 -> (r=q/14, c4=q%14): handles cols c4*4..c4*4+3 of LDS row r.
    // Per p: 8 channels ch0..ch0+7 (ch0 = p*64 + grp*8): 8 coalesced float4
    // loads (each wave-inst = one 896B contiguous granule), pack, 4x b128 LDS
    // writes (one per col, 8 contiguous ch -> spans tile all 32 banks).
    {
        const int q  = lane;
        const int r  = q / 14;
        const int c4 = q % 14;
        const int hs = (h0 + 55 + r) % HH;          // source row for LDS row r
        const float* src0 = xb + (size_t)hs * WW + c4 * 4;
        unsigned short* dstc = &XT[r * XROWSZ + (c4 * 4) * XSTRIDE];
        if (q < WW) {
#pragma unroll
            for (int p = 0; p < 2; ++p) {
                const int ch0 = p * 64 + grp * 8;
                f32x4v v[8];
#pragma unroll
                for (int cc = 0; cc < 8; ++cc)
                    v[cc] = *(const f32x4v*)(src0 + (size_t)(ch0 + cc) * HW);
#pragma unroll
                for (int vc = 0; vc < 4; ++vc) {
                    uint4 w128;
                    w128.x = pk2(v[0][vc], v[1][vc]);
                    w128.y = pk2(v[2][vc], v[3][vc]);
                    w128.z = pk2(v[4][vc], v[5][vc]);
                    w128.w = pk2(v[6][vc], v[7][vc]);
                    *(uint4*)(dstc + vc * XSTRIDE + ch0) = w128;
                }
            }
        }
    }
    __syncthreads();

    // ---- MFMA: wave grp -> row rr = grp>>1, col-half hf = grp&1 ----
    const int l15 = lane & 15;
    const int kb  = (lane >> 4) * 8;
    const int rr  = grp >> 1;
    const int hf  = grp & 1;
    const unsigned short* Xr = &XT[rr * XROWSZ];

    const unsigned short* bp[2][3];
#pragma unroll
    for (int ct2 = 0; ct2 < 2; ++ct2) {
        const int nn = (hf * 2 + ct2) * 16 + l15;
        const int cc0 = (nn >= 1 && nn <= 55) ? (nn + 54) % WW : WW;
        const int cc1 = (nn <= 55) ? (nn + 55) % WW : WW;
        const int cc2 = (nn <= 54) ? nn : WW;
        bp[ct2][0] = Xr + cc0 * XSTRIDE + kb;
        bp[ct2][1] = Xr + cc1 * XSTRIDE + kb;
        bp[ct2][2] = Xr + cc2 * XSTRIDE + kb;
    }

    const unsigned short* wp = ws + l15 * WSTRIDE + kb;

    f32x4 acc[2][2];
#pragma unroll
    for (int ct2 = 0; ct2 < 2; ++ct2) {
        acc[ct2][0] = (f32x4){0.f, 0.f, 0.f, 0.f};
        acc[ct2][1] = (f32x4){0.f, 0.f, 0.f, 0.f};
    }

#pragma unroll
    for (int c = 0; c < 12; ++c) {
        const int tap = c >> 2;
        const int ib  = (c & 3) * 32;
        bf16x8 A0 = *(const bf16x8*)(wp + c * 32);
        bf16x8 A1 = *(const bf16x8*)(wp + 16 * WSTRIDE + c * 32);
#pragma unroll
        for (int ct2 = 0; ct2 < 2; ++ct2) {
            bf16x8 B = *(const bf16x8*)(bp[ct2][tap] + ib);
            acc[ct2][0] = __builtin_amdgcn_mfma_f32_16x16x32_bf16(A0, B, acc[ct2][0], 0, 0, 0);
            acc[ct2][1] = __builtin_amdgcn_mfma_f32_16x16x32_bf16(A1, B, acc[ct2][1], 0, 0, 0);
        }
    }

    // ---- epilogue: C/D layout col=lane&15 (w), row=(lane>>4)*4+reg (j) ----
    {
        const int h  = h0 + rr;
        const int j0 = (lane >> 4) * 4;
        float* ob = out + (size_t)n * (C_OUT * HW) + (size_t)h * WW;
#pragma unroll
        for (int ct2 = 0; ct2 < 2; ++ct2) {
            const int nn = (hf * 2 + ct2) * 16 + l15;
            if (nn < WW) {
#pragma unroll
                for (int r = 0; r < 4; ++r) {
                    ob[(size_t)(j0 + r) * HW + nn]      = acc[ct2][0][r];
                    ob[(size_t)(j0 + r + 16) * HW + nn] = acc[ct2][1][r];
                }
            }
        }
    }
}

extern "C" void kernel_launch(void* const* d_in, const int* in_sizes, int n_in,
                              void* d_out, int out_size, void* d_ws, size_t ws_size,
                              hipStream_t stream) {
    const float* x = (const float*)d_in[0];
    const float* w = (const float*)d_in[1];
    float* out = (float*)d_out;
    unsigned short* ws = (unsigned short*)d_ws;   // 32*392*2 = 25088 B needed

    pack_w_kernel<<<(C_OUT * WSTRIDE + 255) / 256, 256, 0, stream>>>(w, ws);
    conv_mfma_kernel<<<dim3(128 * (HH / 4)), dim3(512), 0, stream>>>(x, ws, out);
}